// Round 6
// baseline (117.762 us; speedup 1.0000x reference)
//
#include <hip/hip_runtime.h>

typedef __attribute__((ext_vector_type(8))) short short8;
typedef __attribute__((ext_vector_type(4))) float floatx4;
typedef __attribute__((ext_vector_type(4))) unsigned int uint32x4;

#define CIN  256
#define NSP  2048   // T*H*W
#define COUT 256
#define FF   512
#define NSHARD 32
#define PITCH 128   // u32 per n-row of the transposed bf16 panel (no pad;
                    // bank spread comes from the XOR swizzle below)

// Module-scope scratch (d_ws unused; harness's 256 MiB ws poison-fill is
// unconditional -- round 2 -- so workspace vs globals is perf-neutral).
__device__ unsigned short g_M[COUT * CIN];        // 128 KiB bf16 M = Wout @ Wv
// Sharded BN partials: 32 shards x {sum,sumsq} x 256 oc -> 8 atomics/address.
__device__ float g_shard[NSHARD][2][COUT];        // 64 KiB

__device__ __forceinline__ unsigned short f2bf_rne(float f) {
  unsigned int u = __float_as_uint(f);
  u += 0x7fffu + ((u >> 16) & 1u);
  return (unsigned short)(u >> 16);
}

// pack two f32 -> bf16x2 (round-half-up: +0x8000 then take hi16) in 3 VALU
__device__ __forceinline__ unsigned int pack_bf16_hu(float lo, float hi) {
  unsigned int a = __float_as_uint(lo) + 0x8000u;
  unsigned int b = __float_as_uint(hi) + 0x8000u;
  return __builtin_amdgcn_perm(b, a, 0x07060302u);
}

// ---------------------------------------------------------------------------
// K1: M = Wout @ Wv (bf16). 64 blocks x 4 rows x 1024 threads: Wv L2 traffic
// 128 MB (round-5: 1 row/block) -> 32 MB, each Wv dword reused for 4 rows.
// Block 0 zeroes the BN shards.
// ---------------------------------------------------------------------------
__global__ __launch_bounds__(1024) void k1_m(
    const float* __restrict__ Wv, const float* __restrict__ Wout)
{
  __shared__ float ws[4 * FF];        // 4 Wout rows, 8 KiB
  __shared__ float red[4][4][256];    // [f-chunk][row][c], 16 KiB
  const int tid = threadIdx.x;
  const int r0  = blockIdx.x * 4;
  if (blockIdx.x == 0) {
    float* gs = &g_shard[0][0][0];    // 16384 floats
    #pragma unroll
    for (int i = 0; i < 16; ++i) gs[tid + i * 1024] = 0.f;
  }
  ws[tid]        = Wout[(size_t)r0 * FF + tid];
  ws[tid + 1024] = Wout[(size_t)r0 * FF + 1024 + tid];
  __syncthreads();
  const int c  = tid & 255;
  const int fs = tid >> 8;            // f-chunk, constant per wave -> ws bcast
  float a0 = 0.f, a1 = 0.f, a2 = 0.f, a3 = 0.f;
  #pragma unroll 8
  for (int f0 = 0; f0 < 128; ++f0) {
    const int f = fs * 128 + f0;
    const float wv = Wv[(size_t)f * 256 + c];   // coalesced, L2-hot
    a0 += ws[f] * wv;
    a1 += ws[FF + f] * wv;
    a2 += ws[2 * FF + f] * wv;
    a3 += ws[3 * FF + f] * wv;
  }
  red[fs][0][c] = a0; red[fs][1][c] = a1;
  red[fs][2][c] = a2; red[fs][3][c] = a3;
  __syncthreads();
  const int rr = tid >> 8, cc = tid & 255;      // all 1024 threads: 4r x 256c
  float s = red[0][rr][cc] + red[1][rr][cc] + red[2][rr][cc] + red[3][rr][cc];
  g_M[(size_t)(r0 + rr) * 256 + cc] = f2bf_rne(s);
}

// ---------------------------------------------------------------------------
// K2: o = M @ x via bf16 MFMA. The block's x panel is staged into LDS as
// *bf16, transposed* [n][c-pair]: the f32->bf16 pack happens ONCE at stage
// time (round-5 packed per-consumer: 192 VALU + 128 ds_read_b32 per thread
// in the MFMA dependency path, 4x redundant across oc-waves). A B-fragment
// is now one 16B ds_read_b128.
// XOR swizzle idx ^= (n&7)<<2: start bank-group = ((w>>2) ^ (n&7)) & 7 is a
// permutation over the 8 4-bank groups for both the staging b128 writes
// (w>>2 = wv*4+cq vs n&7) and frag reads (kk*4+q vs n&7 over 16 m16 rows)
// -> every b128 op hits all 32 banks uniformly = conflict-free. 16B align
// preserved (XOR flips idx bits 2..4 only).
// Residual re-read from global f32 x (XCD-L2-hot; full precision).
// 256 blocks x 512 thr; XCD pin b = id&7 (256%8==0, bijective).
// ---------------------------------------------------------------------------
__global__ __launch_bounds__(512, 4) void k2_gemm(
    const float* __restrict__ x, const float* __restrict__ bout,
    float* __restrict__ out)
{
  __shared__ __align__(16) unsigned int lxt[64 * PITCH];  // 32 KiB bf16 panel^T
  __shared__ float ls[COUT], lq[COUT];
  const int tid  = threadIdx.x;
  const int lane = tid & 63;
  const int wave = tid >> 6;
  const int m16  = lane & 15;
  const int q    = lane >> 4;
  const int id   = blockIdx.x;
  const int b    = id & 7;            // XCD pin: batch b -> XCD b
  const int n0   = (id >> 3) * 64;    // 32 n-panels per batch
  const int wocb = (wave & 3) * 64;   // wave's 64 oc rows (4 oc-waves)
  const int wn   = (wave >> 2) * 32;  // wave's 32 n cols  (2 n-waves)

  if (tid < COUT) { ls[tid] = 0.f; lq[tid] = 0.f; }

  // ---- stage x[b][0:256][n0:n0+64] -> bf16, transposed, swizzled ----
  {
    const int cgrp = tid >> 4;        // 0..31: 8-row c group
    const int n4   = tid & 15;        // 16 n4-groups of 4 n
    const int c0   = cgrp * 8;
    const float* gp = x + (size_t)b * CIN * NSP + (size_t)c0 * NSP + n0 + n4 * 4;
    float4 v[8];
    #pragma unroll
    for (int i = 0; i < 8; ++i)       // rows c0..c0+7: 256B-contig per 16 lanes
      v[i] = *(const float4*)(gp + (size_t)i * NSP);
    const float* vf = (const float*)v;  // v[i] component j = vf[i*4+j]
    #pragma unroll
    for (int j = 0; j < 4; ++j) {
      uint32x4 w;
      #pragma unroll
      for (int p = 0; p < 4; ++p)     // c-pair (c0+2p, c0+2p+1), col n4*4+j
        w[p] = pack_bf16_hu(vf[(2 * p) * 4 + j], vf[(2 * p + 1) * 4 + j]);
      const int n = n4 * 4 + j;
      const int idx = (n * PITCH + cgrp * 4) ^ ((n & 7) << 2);
      *(uint32x4*)&lxt[idx] = w;      // ds_write_b128, conflict-free
    }
  }
  __syncthreads();

  floatx4 acc[4][2];
  #pragma unroll
  for (int i = 0; i < 4; ++i)
    #pragma unroll
    for (int j = 0; j < 2; ++j)
      acc[i][j] = (floatx4){0.f, 0.f, 0.f, 0.f};

  const unsigned short* Ab = g_M + (size_t)(wocb + m16) * 256 + q * 8;

  #pragma unroll
  for (int kk = 0; kk < 8; ++kk) {
    short8 av[4];
    #pragma unroll
    for (int ti = 0; ti < 4; ++ti)    // 16B L2-hot loads of M
      av[ti] = *(const short8*)(Ab + (size_t)ti * 16 * 256 + kk * 32);
    short8 bv[2];
    #pragma unroll
    for (int tj = 0; tj < 2; ++tj) {  // one ds_read_b128 per fragment
      const int n = wn + tj * 16 + m16;
      const int idx = (n * PITCH + kk * 16 + q * 4) ^ ((n & 7) << 2);
      bv[tj] = *(const short8*)&lxt[idx];
    }
    #pragma unroll
    for (int ti = 0; ti < 4; ++ti)
      #pragma unroll
      for (int tj = 0; tj < 2; ++tj)
        acc[ti][tj] = __builtin_amdgcn_mfma_f32_16x16x32_bf16(av[ti], bv[tj], acc[ti][tj], 0, 0, 0);
  }

  // D layout: col(n)=lane&15, row(oc within 16-tile)=q*4+reg
  #pragma unroll
  for (int ti = 0; ti < 4; ++ti) {
    #pragma unroll
    for (int r = 0; r < 4; ++r) {
      const int oc = wocb + ti * 16 + q * 4 + r;
      const float bo = bout[oc];
      float s = 0.f, s2 = 0.f;
      #pragma unroll
      for (int tj = 0; tj < 2; ++tj) {
        const int nl = wn + tj * 16 + m16;
        const size_t gidx = ((size_t)(b * COUT + oc)) * NSP + n0 + nl;
        float o = fmaxf(acc[ti][tj][r] + bo, 0.f);
        float y = x[gidx] + o;        // residual: f32, XCD-L2-hot
        out[gidx] = y;                // f32, 64B sectors per 16-lane group
        s += y;
        s2 += y * y;
      }
      #pragma unroll
      for (int d = 1; d < 16; d <<= 1) {  // stays within 16-lane group
        s  += __shfl_xor(s, d, 64);
        s2 += __shfl_xor(s2, d, 64);
      }
      if (m16 == 0) {
        atomicAdd(&ls[oc], s);
        atomicAdd(&lq[oc], s2);
      }
    }
  }
  __syncthreads();
  if (tid < COUT) {
    const int s = id >> 3;            // 32 shards; 8 atomics/address (8 b's)
    atomicAdd(&g_shard[s][0][tid], ls[tid]);
    atomicAdd(&g_shard[s][1][tid], lq[tid]);
  }
}

// ---------------------------------------------------------------------------
// K3: normalize out in place. 2048 blocks, XCD-pinned like K2 (b = id&7) so
// batch b's rows are re-read from the XCD-L2 that K2 just wrote them to.
// Shard sum: 64 uniform scalar-path loads, L2-hot.
// ---------------------------------------------------------------------------
__global__ __launch_bounds__(256) void k3_norm(
    const float* __restrict__ gamma, const float* __restrict__ beta,
    float* __restrict__ out)
{
  const int id = blockIdx.x;
  const int b  = id & 7;              // XCD pin, matches K2's writer
  const int oc = id >> 3;             // 0..255
  float su = 0.f, sq = 0.f;
  #pragma unroll
  for (int i = 0; i < NSHARD; ++i) {
    su += g_shard[i][0][oc];
    sq += g_shard[i][1][oc];
  }
  const float inv_n = 1.f / 16384.f;
  const float m  = su * inv_n;
  const float v  = sq * inv_n - m * m;
  const float sc = gamma[oc] * rsqrtf(v + 1e-5f);
  const float sh = beta[oc] - m * sc;
  float* p = out + ((size_t)(b * COUT + oc)) * NSP + threadIdx.x * 8;
  float4 a = *(const float4*)p;
  float4 c = *(const float4*)(p + 4);
  a.x = a.x * sc + sh; a.y = a.y * sc + sh;
  a.z = a.z * sc + sh; a.w = a.w * sc + sh;
  c.x = c.x * sc + sh; c.y = c.y * sc + sh;
  c.z = c.z * sc + sh; c.w = c.w * sc + sh;
  *(float4*)p = a;
  *(float4*)(p + 4) = c;
}

extern "C" void kernel_launch(void* const* d_in, const int* in_sizes, int n_in,
                              void* d_out, int out_size, void* d_ws, size_t ws_size,
                              hipStream_t stream) {
  const float* x     = (const float*)d_in[0];
  // d_in[1]=Wk, d_in[2]=Wq: dead — softmax rows sum to 1, so agg == V,
  // and o = Wout@(Wv@x) = (Wout@Wv)@x = M@x.
  const float* Wv    = (const float*)d_in[3];
  const float* Wout  = (const float*)d_in[4];
  const float* bout  = (const float*)d_in[5];
  const float* gamma = (const float*)d_in[6];
  const float* beta  = (const float*)d_in[7];
  float* out = (float*)d_out;

  hipLaunchKernelGGL(k1_m,    dim3(64),   dim3(1024), 0, stream, Wv, Wout);
  hipLaunchKernelGGL(k2_gemm, dim3(256),  dim3(512),  0, stream, x, bout, out);
  hipLaunchKernelGGL(k3_norm, dim3(2048), dim3(256),  0, stream,
                     gamma, beta, out);
}